// Round 1
// baseline (457.367 us; speedup 1.0000x reference)
//
#include <hip/hip_runtime.h>
#include <math.h>

#define NB 8
#define CDIM 256
#define HWD 1024
#define NH 8
#define HD 32
#define NN 102
#define GD 64

// ---------------- weight transpose (32x32 LDS tiles) ----------------
__global__ __launch_bounds__(256) void transpose_k(const float* __restrict__ in,
                                                   float* __restrict__ out, int R, int C) {
  __shared__ float tile[32][33];
  int c0 = blockIdx.x * 32, r0 = blockIdx.y * 32;
  for (int i = threadIdx.y; i < 32; i += 8) {
    int r = r0 + i, c = c0 + threadIdx.x;
    if (r < R && c < C) tile[i][threadIdx.x] = in[r * C + c];
  }
  __syncthreads();
  for (int i = threadIdx.y; i < 32; i += 8) {
    int c = c0 + i, r = r0 + threadIdx.x;
    if (r < R && c < C) out[c * R + r] = tile[threadIdx.x][i];
  }
}

// ---------------- importance = unbiased variance over channels ----------------
__global__ __launch_bounds__(256) void importance_k(const float* __restrict__ x,
                                                    float* __restrict__ imp) {
  int t = blockIdx.x * 256 + threadIdx.x;          // 8192 threads
  int b = t >> 10, p = t & 1023;
  const float* xp = x + (size_t)b * CDIM * HWD + p;
  float s = 0.f;
  for (int c = 0; c < CDIM; ++c) s += xp[c * HWD];
  float mean = s * (1.f / CDIM);
  float v = 0.f;
  for (int c = 0; c < CDIM; ++c) { float d = xp[c * HWD] - mean; v += d * d; }
  imp[t] = v * (1.f / (CDIM - 1));
}

// ---------------- top-102 per batch via bitonic sort ----------------
__global__ __launch_bounds__(1024) void topk_k(const float* __restrict__ imp,
                                               int* __restrict__ topi, int* __restrict__ nodeof) {
  __shared__ float sv[1024];
  __shared__ int si[1024];
  int b = blockIdx.x, t = threadIdx.x;
  sv[t] = imp[b * 1024 + t];
  si[t] = t;
  nodeof[b * 1024 + t] = -1;
  __syncthreads();
  for (int k = 2; k <= 1024; k <<= 1) {
    for (int j = k >> 1; j > 0; j >>= 1) {
      int ixj = t ^ j;
      if (ixj > t) {
        bool up = ((t & k) == 0);
        float a = sv[t], c = sv[ixj];
        if ((a > c) == up) {
          sv[t] = c; sv[ixj] = a;
          int ti = si[t]; si[t] = si[ixj]; si[ixj] = ti;
        }
      }
      __syncthreads();
    }
  }
  if (t >= 1024 - NN) {           // ascending sort: largest at the end
    int n = 1023 - t;             // n = 0 is the max (order is irrelevant downstream)
    int idx = si[t];
    topi[b * 128 + n] = idx;
    nodeof[b * 1024 + idx] = n;
  }
}

// ---------------- gather node feats + reciprocal norms ----------------
__global__ __launch_bounds__(256) void feats_k(const float* __restrict__ x,
                                               const int* __restrict__ topi,
                                               float* __restrict__ feats, float* __restrict__ rn) {
  int n = blockIdx.x, b = blockIdx.y, t = threadIdx.x;   // 256 threads, t = channel
  int idx = topi[b * 128 + n];
  float v = x[((size_t)b * CDIM + t) * HWD + idx];
  feats[((size_t)b * NN + n) * CDIM + t] = v;
  float ss = v * v;
  for (int m = 1; m < 64; m <<= 1) ss += __shfl_xor(ss, m);
  __shared__ float red[4];
  if ((t & 63) == 0) red[t >> 6] = ss;
  __syncthreads();
  if (t == 0) {
    float tot = red[0] + red[1] + red[2] + red[3];
    rn[b * 128 + n] = 1.f / fmaxf(sqrtf(tot), 1e-12f);
  }
}

// ---------------- cosine-sim adjacency (+ self loops) ----------------
__global__ __launch_bounds__(128) void adj_k(const float* __restrict__ feats,
                                             const float* __restrict__ rn,
                                             unsigned char* __restrict__ adj) {
  int i = blockIdx.x, b = blockIdx.y, t = threadIdx.x;   // 128 threads
  __shared__ float fi[CDIM];
  for (int c = t; c < CDIM; c += 128) fi[c] = feats[((size_t)b * NN + i) * CDIM + c];
  __syncthreads();
  if (t < NN) {
    const float* fj = feats + ((size_t)b * NN + t) * CDIM;
    float d = 0.f;
    for (int c = 0; c < CDIM; ++c) d += fi[c] * fj[c];
    float sim = d * rn[b * 128 + i] * rn[b * 128 + t];
    adj[((size_t)b * NN + i) * NN + t] = (sim > 0.6f || t == i) ? 1 : 0;
  }
}

// ---------------- GAT: h = in @ W ; asrc/adst dots ----------------
__global__ __launch_bounds__(64) void gath_k(const float* __restrict__ in,
                                             const float* __restrict__ W,
                                             const float* __restrict__ aw_src,
                                             const float* __restrict__ aw_dst,
                                             float* __restrict__ h, float* __restrict__ asrc,
                                             float* __restrict__ adst, int Fin) {
  int n = blockIdx.x, b = blockIdx.y, f = threadIdx.x;   // 64 threads
  __shared__ float il[CDIM];
  const float* ip = in + ((size_t)b * NN + n) * Fin;
  for (int c = f; c < Fin; c += 64) il[c] = ip[c];
  __syncthreads();
  float acc = 0.f;
  for (int c = 0; c < Fin; ++c) acc += il[c] * W[c * GD + f];
  h[((size_t)b * NN + n) * GD + f] = acc;
  float s1 = acc * aw_src[f], s2 = acc * aw_dst[f];
  for (int m = 1; m < 64; m <<= 1) { s1 += __shfl_xor(s1, m); s2 += __shfl_xor(s2, m); }
  if (f == 0) { asrc[b * 128 + n] = s1; adst[b * 128 + n] = s2; }
}

// ---------------- GAT: masked softmax + aggregate + bias + relu ----------------
__global__ __launch_bounds__(128) void gatsoft_k(const float* __restrict__ h,
                                                 const float* __restrict__ asrc,
                                                 const float* __restrict__ adst,
                                                 const unsigned char* __restrict__ adj,
                                                 const float* __restrict__ bias,
                                                 float* __restrict__ out) {
  int i = blockIdx.x, b = blockIdx.y, t = threadIdx.x;   // 128 threads
  __shared__ float alpha[NN];
  __shared__ float red[2];
  float adsti = adst[b * 128 + i];
  float e = -1e30f;
  if (t < NN && adj[((size_t)b * NN + i) * NN + t]) {
    float z = adsti + asrc[b * 128 + t];
    e = (z > 0.f) ? z : 0.2f * z;
  }
  float m = e;
  for (int mm = 1; mm < 64; mm <<= 1) m = fmaxf(m, __shfl_xor(m, mm));
  if ((t & 63) == 0) red[t >> 6] = m;
  __syncthreads();
  m = fmaxf(red[0], red[1]);
  float p = (t < NN) ? __expf(e - m) : 0.f;
  float s = p;
  for (int mm = 1; mm < 64; mm <<= 1) s += __shfl_xor(s, mm);
  __syncthreads();
  if ((t & 63) == 0) red[t >> 6] = s;
  __syncthreads();
  s = red[0] + red[1];
  if (t < NN) alpha[t] = p / s;
  __syncthreads();
  if (t < GD) {
    float o = 0.f;
    for (int j = 0; j < NN; ++j) o += alpha[j] * h[((size_t)b * NN + j) * GD + t];
    o += bias[t];
    out[((size_t)b * NN + i) * GD + t] = fmaxf(o, 0.f);
  }
}

// ---------------- graph-to-attn gate ----------------
__global__ __launch_bounds__(64) void g2a_k(const float* __restrict__ g,
                                            const float* __restrict__ w,
                                            const float* __restrict__ bias,
                                            float* __restrict__ gw) {
  int n = blockIdx.x, b = blockIdx.y, t = threadIdx.x;   // 64 threads
  __shared__ float gl[GD];
  gl[t] = g[((size_t)b * NN + n) * GD + t];
  __syncthreads();
  if (t < NH) {
    float acc = bias[t];
    for (int c = 0; c < GD; ++c) acc += gl[c] * w[t * GD + c];
    gw[((size_t)b * NN + n) * NH + t] = 1.f / (1.f + __expf(-acc));
  }
}

#define FMA16(acc, av, bv)                                                            \
  acc[0][0] += av.x * bv.x; acc[0][1] += av.x * bv.y; acc[0][2] += av.x * bv.z;       \
  acc[0][3] += av.x * bv.w;                                                           \
  acc[1][0] += av.y * bv.x; acc[1][1] += av.y * bv.y; acc[1][2] += av.y * bv.z;       \
  acc[1][3] += av.y * bv.w;                                                           \
  acc[2][0] += av.z * bv.x; acc[2][1] += av.z * bv.y; acc[2][2] += av.z * bv.z;       \
  acc[2][3] += av.z * bv.w;                                                           \
  acc[3][0] += av.w * bv.x; acc[3][1] += av.w * bv.y; acc[3][2] += av.w * bv.z;       \
  acc[3][3] += av.w * bv.w;

// ---------------- QKV GEMM: [8192,256] @ wqkvT[256,768] -> q/k/v [b][h][p][d] ----------------
__global__ __launch_bounds__(256) void qkv_k(const float* __restrict__ x,
                                             const float* __restrict__ wT,
                                             float* __restrict__ qkv) {
  __shared__ float a_s[16][68];
  __shared__ float b_s[16][68];
  int m0 = blockIdx.x * 64, n0 = blockIdx.y * 64;
  int b = m0 >> 10, p0 = m0 & 1023;
  int t = threadIdx.x, tx = t & 15, ty = t >> 4;
  float acc[4][4] = {};
  for (int k0 = 0; k0 < 256; k0 += 16) {
    int m = t & 63, kb = t >> 6;
#pragma unroll
    for (int r = 0; r < 4; ++r) {
      int kk = kb * 4 + r;
      a_s[kk][m] = x[((size_t)b * 256 + k0 + kk) * 1024 + p0 + m];   // x is [c][p]: free transpose
      b_s[kk][m] = wT[(k0 + kk) * 768 + n0 + m];
    }
    __syncthreads();
#pragma unroll
    for (int kk = 0; kk < 16; ++kk) {
      float4 av = *(const float4*)&a_s[kk][ty * 4];
      float4 bv = *(const float4*)&b_s[kk][tx * 4];
      FMA16(acc, av, bv)
    }
    __syncthreads();
  }
  const float scale = 0.17677669529663687f;   // hd^-0.5 folded into Q
  int n = n0 + tx * 4;
  int qi = n >> 8, hh = (n >> 5) & 7, d = n & 31;
  float mul = (qi == 0) ? scale : 1.f;
#pragma unroll
  for (int i = 0; i < 4; ++i) {
    int p = p0 + ty * 4 + i;
    float4 v4 = {acc[i][0] * mul, acc[i][1] * mul, acc[i][2] * mul, acc[i][3] * mul};
    *(float4*)&qkv[(((size_t)qi * 8 + b) * 8 + hh) * 32768 + (size_t)p * 32 + d] = v4;
  }
}

// ---------------- flash attention + graph modulation ----------------
__global__ __launch_bounds__(256) void attn_k(const float* __restrict__ qkv,
                                              const int* __restrict__ nodeof,
                                              const float* __restrict__ gw,
                                              const unsigned char* __restrict__ adj,
                                              float* __restrict__ ao) {
  __shared__ float q_s[32][68];   // d-major
  __shared__ float k_s[32][68];   // d-major
  __shared__ float v_s[64][36];   // k-major
  __shared__ float p_s[64][68];
  __shared__ int jcol[64];
  __shared__ float gcol[64];
  __shared__ int irow[64];
  __shared__ float growq[64];
  int qt = blockIdx.x, bh = blockIdx.y;
  int b = bh >> 3, h = bh & 7;
  int q0 = qt * 64;
  const float* Qp = qkv + (size_t)bh * 32768;
  const float* Kp = Qp + (size_t)2097152;
  const float* Vp = Qp + (size_t)2 * 2097152;
  int t = threadIdx.x, tx = t & 15, ty = t >> 4;
  {
    int pl = t & 63, dbase = (t >> 6) * 4;
#pragma unroll
    for (int r = 0; r < 2; ++r) {
      int d0 = dbase + r * 16;
      float4 v4 = *(const float4*)&Qp[(size_t)(q0 + pl) * 32 + d0];
      q_s[d0 + 0][pl] = v4.x; q_s[d0 + 1][pl] = v4.y;
      q_s[d0 + 2][pl] = v4.z; q_s[d0 + 3][pl] = v4.w;
    }
    if (t < 64) {
      int in_ = nodeof[b * 1024 + q0 + t];
      irow[t] = in_;
      growq[t] = (in_ >= 0) ? gw[((size_t)b * NN + in_) * NH + h] : 0.f;
    }
  }
  float o[4][2] = {};
  float m_r[4] = {-INFINITY, -INFINITY, -INFINITY, -INFINITY};
  float l_r[4] = {};
  const unsigned char* adjB = adj + (size_t)b * NN * NN;
  for (int ch = 0; ch < 16; ++ch) {
    int c0 = ch * 64;
    __syncthreads();   // prev PV done (and q_s visible on first iter)
    {
      int pl = t & 63, dbase = (t >> 6) * 4;
#pragma unroll
      for (int r = 0; r < 2; ++r) {
        int d0 = dbase + r * 16;
        float4 kk4 = *(const float4*)&Kp[(size_t)(c0 + pl) * 32 + d0];
        k_s[d0 + 0][pl] = kk4.x; k_s[d0 + 1][pl] = kk4.y;
        k_s[d0 + 2][pl] = kk4.z; k_s[d0 + 3][pl] = kk4.w;
        float4 vv4 = *(const float4*)&Vp[(size_t)(c0 + pl) * 32 + d0];
        v_s[pl][d0 + 0] = vv4.x; v_s[pl][d0 + 1] = vv4.y;
        v_s[pl][d0 + 2] = vv4.z; v_s[pl][d0 + 3] = vv4.w;
      }
      if (t < 64) {
        int j = nodeof[b * 1024 + c0 + t];
        jcol[t] = j;
        gcol[t] = (j >= 0) ? gw[((size_t)b * NN + j) * NH + h] : 0.f;
      }
    }
    __syncthreads();
    float s[4][4] = {};
#pragma unroll
    for (int d4 = 0; d4 < 8; ++d4) {
#pragma unroll
      for (int u = 0; u < 4; ++u) {
        int d = d4 * 4 + u;
        float4 av = *(const float4*)&q_s[d][ty * 4];
        float4 bv = *(const float4*)&k_s[d][tx * 4];
        FMA16(s, av, bv)
      }
    }
    // graph modulation (scale already folded into Q)
    {
      int jn0 = jcol[tx * 4 + 0], jn1 = jcol[tx * 4 + 1];
      int jn2 = jcol[tx * 4 + 2], jn3 = jcol[tx * 4 + 3];
      float gc0 = gcol[tx * 4 + 0], gc1 = gcol[tx * 4 + 1];
      float gc2 = gcol[tx * 4 + 2], gc3 = gcol[tx * 4 + 3];
#pragma unroll
      for (int i = 0; i < 4; ++i) {
        int in_ = irow[ty * 4 + i];
        if (in_ >= 0) {
          const unsigned char* ar = adjB + (size_t)in_ * NN;
          float gq = growq[ty * 4 + i];
          if (jn0 >= 0 && ar[jn0]) s[i][0] += gq * gc0;
          if (jn1 >= 0 && ar[jn1]) s[i][1] += gq * gc1;
          if (jn2 >= 0 && ar[jn2]) s[i][2] += gq * gc2;
          if (jn3 >= 0 && ar[jn3]) s[i][3] += gq * gc3;
        }
      }
    }
    // online softmax (rows owned by 16 consecutive lanes; xor masks 1,2,4,8)
#pragma unroll
    for (int i = 0; i < 4; ++i) {
      float mx = fmaxf(fmaxf(s[i][0], s[i][1]), fmaxf(s[i][2], s[i][3]));
      mx = fmaxf(mx, __shfl_xor(mx, 1));
      mx = fmaxf(mx, __shfl_xor(mx, 2));
      mx = fmaxf(mx, __shfl_xor(mx, 4));
      mx = fmaxf(mx, __shfl_xor(mx, 8));
      float mn = fmaxf(m_r[i], mx);
      float al = __expf(m_r[i] - mn);
      float p0 = __expf(s[i][0] - mn);
      float p1 = __expf(s[i][1] - mn);
      float p2 = __expf(s[i][2] - mn);
      float p3 = __expf(s[i][3] - mn);
      float ls = p0 + p1 + p2 + p3;
      ls += __shfl_xor(ls, 1); ls += __shfl_xor(ls, 2);
      ls += __shfl_xor(ls, 4); ls += __shfl_xor(ls, 8);
      l_r[i] = l_r[i] * al + ls;
      m_r[i] = mn;
      o[i][0] *= al; o[i][1] *= al;
      float4 pv = {p0, p1, p2, p3};
      *(float4*)&p_s[ty * 4 + i][tx * 4] = pv;
    }
    __syncthreads();
#define PVSTEP(kk, comp)                                                   \
    {                                                                      \
      float2 vv = *(const float2*)&v_s[k4 * 4 + kk][tx * 2];               \
      o[0][0] += pr0.comp * vv.x; o[0][1] += pr0.comp * vv.y;              \
      o[1][0] += pr1.comp * vv.x; o[1][1] += pr1.comp * vv.y;              \
      o[2][0] += pr2.comp * vv.x; o[2][1] += pr2.comp * vv.y;              \
      o[3][0] += pr3.comp * vv.x; o[3][1] += pr3.comp * vv.y;              \
    }
#pragma unroll
    for (int k4 = 0; k4 < 16; ++k4) {
      float4 pr0 = *(const float4*)&p_s[ty * 4 + 0][k4 * 4];
      float4 pr1 = *(const float4*)&p_s[ty * 4 + 1][k4 * 4];
      float4 pr2 = *(const float4*)&p_s[ty * 4 + 2][k4 * 4];
      float4 pr3 = *(const float4*)&p_s[ty * 4 + 3][k4 * 4];
      PVSTEP(0, x) PVSTEP(1, y) PVSTEP(2, z) PVSTEP(3, w)
    }
#undef PVSTEP
  }
#pragma unroll
  for (int i = 0; i < 4; ++i) {
    float inv = 1.f / l_r[i];
    float2 r2 = {o[i][0] * inv, o[i][1] * inv};
    *(float2*)&ao[(size_t)(b * 1024 + q0 + ty * 4 + i) * 256 + h * 32 + tx * 2] = r2;
  }
}

// ---------------- proj GEMM + bias + transposed store ----------------
__global__ __launch_bounds__(256) void proj_k(const float* __restrict__ ao,
                                              const float* __restrict__ wT,
                                              const float* __restrict__ bias,
                                              float* __restrict__ out) {
  __shared__ float a_s[16][68];
  __shared__ float b_s[16][68];
  __shared__ float c_s[64][68];
  int m0 = blockIdx.x * 64, n0 = blockIdx.y * 64;
  int b = m0 >> 10, p0 = m0 & 1023;
  int t = threadIdx.x, tx = t & 15, ty = t >> 4;
  float acc[4][4] = {};
  for (int k0 = 0; k0 < 256; k0 += 16) {
    {
      int kk = t & 15, mm = t >> 4;
#pragma unroll
      for (int r = 0; r < 4; ++r) {
        int m = mm + r * 16;
        a_s[kk][m] = ao[(size_t)(m0 + m) * 256 + k0 + kk];
      }
      int mB = t & 63, kb = t >> 6;
#pragma unroll
      for (int r2 = 0; r2 < 4; ++r2) {
        int kk2 = kb * 4 + r2;
        b_s[kk2][mB] = wT[(k0 + kk2) * 256 + n0 + mB];
      }
    }
    __syncthreads();
#pragma unroll
    for (int kk = 0; kk < 16; ++kk) {
      float4 av = *(const float4*)&a_s[kk][ty * 4];
      float4 bv = *(const float4*)&b_s[kk][tx * 4];
      FMA16(acc, av, bv)
    }
    __syncthreads();
  }
#pragma unroll
  for (int i = 0; i < 4; ++i)
#pragma unroll
    for (int j = 0; j < 4; ++j) c_s[tx * 4 + j][ty * 4 + i] = acc[i][j];
  __syncthreads();
  {
    int cl = t >> 2, pg = t & 3;
    float bv = bias[n0 + cl];
#pragma unroll
    for (int r = 0; r < 4; ++r) {
      int p = pg * 16 + r * 4;
      float4 v4 = {c_s[cl][p] + bv, c_s[cl][p + 1] + bv, c_s[cl][p + 2] + bv, c_s[cl][p + 3] + bv};
      *(float4*)&out[((size_t)b * 256 + n0 + cl) * 1024 + p0 + p] = v4;
    }
  }
}

extern "C" void kernel_launch(void* const* d_in, const int* in_sizes, int n_in,
                              void* d_out, int out_size, void* d_ws, size_t ws_size,
                              hipStream_t stream) {
  const float* x      = (const float*)d_in[0];
  const float* w_qkv  = (const float*)d_in[1];
  const float* w_proj = (const float*)d_in[2];
  const float* b_proj = (const float*)d_in[3];
  const float* g0W    = (const float*)d_in[4];
  const float* g0as   = (const float*)d_in[5];
  const float* g0ad   = (const float*)d_in[6];
  const float* g0b    = (const float*)d_in[7];
  const float* g1W    = (const float*)d_in[8];
  const float* g1as   = (const float*)d_in[9];
  const float* g1ad   = (const float*)d_in[10];
  const float* g1b    = (const float*)d_in[11];
  const float* wg2a   = (const float*)d_in[12];
  const float* bg2a   = (const float*)d_in[13];
  float* out = (float*)d_out;
  float* ws = (float*)d_ws;

  size_t o = 0;
  auto alloc = [&](size_t nf) { float* p = ws + o; o += (nf + 15) & ~(size_t)15; return p; };
  float* wqkvT  = alloc(256 * 768);
  float* wprojT = alloc(256 * 256);
  float* imp    = alloc(8 * 1024);
  int*   topi   = (int*)alloc(8 * 128);
  int*   nodeof = (int*)alloc(8 * 1024);
  float* rn     = alloc(8 * 128);
  float* feats  = alloc(8 * NN * 256);
  unsigned char* adj = (unsigned char*)alloc((8 * NN * NN + 3) / 4 + 16);
  float* h0     = alloc(8 * NN * 64);
  float* g0     = alloc(8 * NN * 64);
  float* h1     = alloc(8 * NN * 64);
  float* g1     = alloc(8 * NN * 64);
  float* asrc   = alloc(8 * 128);
  float* adst   = alloc(8 * 128);
  float* gwb    = alloc(8 * NN * 8);
  float* qkv    = alloc((size_t)3 * 8 * 8 * 1024 * 32);
  float* ao     = alloc((size_t)8 * 1024 * 256);
  if (ws_size < o * sizeof(float)) return;   // deterministic guard

  transpose_k<<<dim3(8, 24), dim3(32, 8), 0, stream>>>(w_qkv, wqkvT, 768, 256);
  transpose_k<<<dim3(8, 8), dim3(32, 8), 0, stream>>>(w_proj, wprojT, 256, 256);
  importance_k<<<32, 256, 0, stream>>>(x, imp);
  topk_k<<<8, 1024, 0, stream>>>(imp, topi, nodeof);
  feats_k<<<dim3(NN, 8), 256, 0, stream>>>(x, topi, feats, rn);
  adj_k<<<dim3(NN, 8), 128, 0, stream>>>(feats, rn, adj);
  gath_k<<<dim3(NN, 8), 64, 0, stream>>>(feats, g0W, g0as, g0ad, h0, asrc, adst, 256);
  gatsoft_k<<<dim3(NN, 8), 128, 0, stream>>>(h0, asrc, adst, adj, g0b, g0);
  gath_k<<<dim3(NN, 8), 64, 0, stream>>>(g0, g1W, g1as, g1ad, h1, asrc, adst, 64);
  gatsoft_k<<<dim3(NN, 8), 128, 0, stream>>>(h1, asrc, adst, adj, g1b, g1);
  g2a_k<<<dim3(NN, 8), 64, 0, stream>>>(g1, wg2a, bg2a, gwb);
  qkv_k<<<dim3(128, 12), 256, 0, stream>>>(x, wqkvT, qkv);
  attn_k<<<dim3(16, 64), 256, 0, stream>>>(qkv, nodeof, gwb, adj, ao);
  proj_k<<<dim3(128, 4), 256, 0, stream>>>(ao, wprojT, b_proj, out);
}

// Round 2
// 364.878 us; speedup vs baseline: 1.2535x; 1.2535x over previous
//
#include <hip/hip_runtime.h>
#include <math.h>

#define NB 8
#define CDIM 256
#define HWD 1024
#define NH 8
#define HD 32
#define NN 102
#define GD 64

typedef __attribute__((ext_vector_type(8))) short bf16x8;
typedef __attribute__((ext_vector_type(4))) float f32x4;

__device__ inline short f2bf(float f) {
  union { float f; unsigned u; } v; v.f = f;
  unsigned r = v.u + 0x7fffu + ((v.u >> 16) & 1u);
  return (short)(r >> 16);
}
__device__ inline float bf2f(short s) {
  union { unsigned u; float f; } v;
  v.u = ((unsigned)(unsigned short)s) << 16;
  return v.f;
}

// ---------------- weight transpose (32x32 LDS tiles) ----------------
__global__ __launch_bounds__(256) void transpose_k(const float* __restrict__ in,
                                                   float* __restrict__ out, int R, int C) {
  __shared__ float tile[32][33];
  int c0 = blockIdx.x * 32, r0 = blockIdx.y * 32;
  for (int i = threadIdx.y; i < 32; i += 8) {
    int r = r0 + i, c = c0 + threadIdx.x;
    if (r < R && c < C) tile[i][threadIdx.x] = in[r * C + c];
  }
  __syncthreads();
  for (int i = threadIdx.y; i < 32; i += 8) {
    int c = c0 + i, r = r0 + threadIdx.x;
    if (r < R && c < C) out[c * R + r] = tile[threadIdx.x][i];
  }
}

// ---------------- importance = unbiased variance over channels ----------------
__global__ __launch_bounds__(256) void importance_k(const float* __restrict__ x,
                                                    float* __restrict__ imp) {
  int t = blockIdx.x * 256 + threadIdx.x;
  int b = t >> 10, p = t & 1023;
  const float* xp = x + (size_t)b * CDIM * HWD + p;
  float s = 0.f;
  for (int c = 0; c < CDIM; ++c) s += xp[c * HWD];
  float mean = s * (1.f / CDIM);
  float v = 0.f;
  for (int c = 0; c < CDIM; ++c) { float d = xp[c * HWD] - mean; v += d * d; }
  imp[t] = v * (1.f / (CDIM - 1));
}

// ---------------- top-102 per batch via bitonic sort ----------------
__global__ __launch_bounds__(1024) void topk_k(const float* __restrict__ imp,
                                               int* __restrict__ topi, int* __restrict__ nodeof) {
  __shared__ float sv[1024];
  __shared__ int si[1024];
  int b = blockIdx.x, t = threadIdx.x;
  sv[t] = imp[b * 1024 + t];
  si[t] = t;
  nodeof[b * 1024 + t] = -1;
  __syncthreads();
  for (int k = 2; k <= 1024; k <<= 1) {
    for (int j = k >> 1; j > 0; j >>= 1) {
      int ixj = t ^ j;
      if (ixj > t) {
        bool up = ((t & k) == 0);
        float a = sv[t], c = sv[ixj];
        if ((a > c) == up) {
          sv[t] = c; sv[ixj] = a;
          int ti = si[t]; si[t] = si[ixj]; si[ixj] = ti;
        }
      }
      __syncthreads();
    }
  }
  if (t >= 1024 - NN) {
    int n = 1023 - t;
    int idx = si[t];
    topi[b * 128 + n] = idx;
    nodeof[b * 1024 + idx] = n;
  }
}

// ---------------- gather node feats + reciprocal norms ----------------
__global__ __launch_bounds__(256) void feats_k(const float* __restrict__ x,
                                               const int* __restrict__ topi,
                                               float* __restrict__ feats, float* __restrict__ rn) {
  int n = blockIdx.x, b = blockIdx.y, t = threadIdx.x;
  int idx = topi[b * 128 + n];
  float v = x[((size_t)b * CDIM + t) * HWD + idx];
  feats[((size_t)b * NN + n) * CDIM + t] = v;
  float ss = v * v;
  for (int m = 1; m < 64; m <<= 1) ss += __shfl_xor(ss, m);
  __shared__ float red[4];
  if ((t & 63) == 0) red[t >> 6] = ss;
  __syncthreads();
  if (t == 0) {
    float tot = red[0] + red[1] + red[2] + red[3];
    rn[b * 128 + n] = 1.f / fmaxf(sqrtf(tot), 1e-12f);
  }
}

// ---------------- cosine-sim adjacency (+ self loops) ----------------
__global__ __launch_bounds__(128) void adj_k(const float* __restrict__ feats,
                                             const float* __restrict__ rn,
                                             unsigned char* __restrict__ adj) {
  int i = blockIdx.x, b = blockIdx.y, t = threadIdx.x;
  __shared__ float fi[CDIM];
  for (int c = t; c < CDIM; c += 128) fi[c] = feats[((size_t)b * NN + i) * CDIM + c];
  __syncthreads();
  if (t < NN) {
    const float* fj = feats + ((size_t)b * NN + t) * CDIM;
    float d = 0.f;
    for (int c = 0; c < CDIM; ++c) d += fi[c] * fj[c];
    float sim = d * rn[b * 128 + i] * rn[b * 128 + t];
    adj[((size_t)b * NN + i) * NN + t] = (sim > 0.6f || t == i) ? 1 : 0;
  }
}

// ---------------- GAT: h = in @ W ; asrc/adst dots ----------------
__global__ __launch_bounds__(64) void gath_k(const float* __restrict__ in,
                                             const float* __restrict__ W,
                                             const float* __restrict__ aw_src,
                                             const float* __restrict__ aw_dst,
                                             float* __restrict__ h, float* __restrict__ asrc,
                                             float* __restrict__ adst, int Fin) {
  int n = blockIdx.x, b = blockIdx.y, f = threadIdx.x;
  __shared__ float il[CDIM];
  const float* ip = in + ((size_t)b * NN + n) * Fin;
  for (int c = f; c < Fin; c += 64) il[c] = ip[c];
  __syncthreads();
  float acc = 0.f;
  for (int c = 0; c < Fin; ++c) acc += il[c] * W[c * GD + f];
  h[((size_t)b * NN + n) * GD + f] = acc;
  float s1 = acc * aw_src[f], s2 = acc * aw_dst[f];
  for (int m = 1; m < 64; m <<= 1) { s1 += __shfl_xor(s1, m); s2 += __shfl_xor(s2, m); }
  if (f == 0) { asrc[b * 128 + n] = s1; adst[b * 128 + n] = s2; }
}

// ---------------- GAT: masked softmax + aggregate + bias + relu ----------------
__global__ __launch_bounds__(128) void gatsoft_k(const float* __restrict__ h,
                                                 const float* __restrict__ asrc,
                                                 const float* __restrict__ adst,
                                                 const unsigned char* __restrict__ adj,
                                                 const float* __restrict__ bias,
                                                 float* __restrict__ out) {
  int i = blockIdx.x, b = blockIdx.y, t = threadIdx.x;
  __shared__ float alpha[NN];
  __shared__ float red[2];
  float adsti = adst[b * 128 + i];
  float e = -1e30f;
  if (t < NN && adj[((size_t)b * NN + i) * NN + t]) {
    float z = adsti + asrc[b * 128 + t];
    e = (z > 0.f) ? z : 0.2f * z;
  }
  float m = e;
  for (int mm = 1; mm < 64; mm <<= 1) m = fmaxf(m, __shfl_xor(m, mm));
  if ((t & 63) == 0) red[t >> 6] = m;
  __syncthreads();
  m = fmaxf(red[0], red[1]);
  float p = (t < NN) ? __expf(e - m) : 0.f;
  float s = p;
  for (int mm = 1; mm < 64; mm <<= 1) s += __shfl_xor(s, mm);
  __syncthreads();
  if ((t & 63) == 0) red[t >> 6] = s;
  __syncthreads();
  s = red[0] + red[1];
  if (t < NN) alpha[t] = p / s;
  __syncthreads();
  if (t < GD) {
    float o = 0.f;
    for (int j = 0; j < NN; ++j) o += alpha[j] * h[((size_t)b * NN + j) * GD + t];
    o += bias[t];
    out[((size_t)b * NN + i) * GD + t] = fmaxf(o, 0.f);
  }
}

// ---------------- graph-to-attn gate ----------------
__global__ __launch_bounds__(64) void g2a_k(const float* __restrict__ g,
                                            const float* __restrict__ w,
                                            const float* __restrict__ bias,
                                            float* __restrict__ gw) {
  int n = blockIdx.x, b = blockIdx.y, t = threadIdx.x;
  __shared__ float gl[GD];
  gl[t] = g[((size_t)b * NN + n) * GD + t];
  __syncthreads();
  if (t < NH) {
    float acc = bias[t];
    for (int c = 0; c < GD; ++c) acc += gl[c] * w[t * GD + c];
    gw[((size_t)b * NN + n) * NH + t] = 1.f / (1.f + __expf(-acc));
  }
}

#define FMA16(acc, av, bv)                                                            \
  acc[0][0] += av.x * bv.x; acc[0][1] += av.x * bv.y; acc[0][2] += av.x * bv.z;       \
  acc[0][3] += av.x * bv.w;                                                           \
  acc[1][0] += av.y * bv.x; acc[1][1] += av.y * bv.y; acc[1][2] += av.y * bv.z;       \
  acc[1][3] += av.y * bv.w;                                                           \
  acc[2][0] += av.z * bv.x; acc[2][1] += av.z * bv.y; acc[2][2] += av.z * bv.z;       \
  acc[2][3] += av.z * bv.w;                                                           \
  acc[3][0] += av.w * bv.x; acc[3][1] += av.w * bv.y; acc[3][2] += av.w * bv.z;       \
  acc[3][3] += av.w * bv.w;

// ---------------- QKV GEMM: emits split-bf16 Q/K ([bh][p][32] hi+lo) and V^T bf16 [bh][32][1024] ----------------
__global__ __launch_bounds__(256) void qkv_k(const float* __restrict__ x,
                                             const float* __restrict__ wT,
                                             short* __restrict__ qhp, short* __restrict__ qlp,
                                             short* __restrict__ khp, short* __restrict__ klp,
                                             short* __restrict__ vtp) {
  __shared__ float a_s[16][68];
  __shared__ float b_s[16][68];
  __shared__ float c_s[64][68];
  int m0 = blockIdx.x * 64, n0 = blockIdx.y * 64;
  int b = m0 >> 10, p0 = m0 & 1023;
  int t = threadIdx.x, tx = t & 15, ty = t >> 4;
  float acc[4][4] = {};
  for (int k0 = 0; k0 < 256; k0 += 16) {
    int m = t & 63, kb = t >> 6;
#pragma unroll
    for (int r = 0; r < 4; ++r) {
      int kk = kb * 4 + r;
      a_s[kk][m] = x[((size_t)b * 256 + k0 + kk) * 1024 + p0 + m];
      b_s[kk][m] = wT[(k0 + kk) * 768 + n0 + m];
    }
    __syncthreads();
#pragma unroll
    for (int kk = 0; kk < 16; ++kk) {
      float4 av = *(const float4*)&a_s[kk][ty * 4];
      float4 bv = *(const float4*)&b_s[kk][tx * 4];
      FMA16(acc, av, bv)
    }
    __syncthreads();
  }
  int qi = n0 >> 8;
  if (qi < 2) {
    const float scale = (qi == 0) ? 0.17677669529663687f : 1.f;
    short* hp = (qi == 0) ? qhp : khp;
    short* lp = (qi == 0) ? qlp : klp;
    int n = n0 + tx * 4;
    int hh = (n >> 5) & 7, d = n & 31;
#pragma unroll
    for (int i = 0; i < 4; ++i) {
      int p = p0 + ty * 4 + i;
      size_t e = ((size_t)(b * 8 + hh) * 1024 + p) * 32 + d;
      float v0 = acc[i][0] * scale, v1 = acc[i][1] * scale;
      float v2 = acc[i][2] * scale, v3 = acc[i][3] * scale;
      short4 hi, lo;
      hi.x = f2bf(v0); lo.x = f2bf(v0 - bf2f(hi.x));
      hi.y = f2bf(v1); lo.y = f2bf(v1 - bf2f(hi.y));
      hi.z = f2bf(v2); lo.z = f2bf(v2 - bf2f(hi.z));
      hi.w = f2bf(v3); lo.w = f2bf(v3 - bf2f(hi.w));
      *(short4*)(hp + e) = hi;
      *(short4*)(lp + e) = lo;
    }
  } else {
    // V block: transpose 64p x 64n via LDS, emit Vt[bh][d][p] bf16
#pragma unroll
    for (int i = 0; i < 4; ++i)
      *(float4*)&c_s[ty * 4 + i][tx * 4] = *(float4*)&acc[i][0];
    __syncthreads();
    int dl = t >> 2, pg = t & 3;
    int n = n0 + dl;
    int hh = (n >> 5) & 7, d = n & 31;
    size_t rowb = (size_t)(b * 8 + hh) * 32768 + (size_t)d * 1024 + p0;
#pragma unroll
    for (int r = 0; r < 4; ++r) {
      int pl = pg * 16 + r * 4;
      short4 s4;
      s4.x = f2bf(c_s[pl + 0][dl]);
      s4.y = f2bf(c_s[pl + 1][dl]);
      s4.z = f2bf(c_s[pl + 2][dl]);
      s4.w = f2bf(c_s[pl + 3][dl]);
      *(short4*)(vtp + rowb + pl) = s4;
    }
  }
}

// ---------------- flash attention, split-bf16 MFMA + graph modulation ----------------
// Per wave: 32 q-rows; S = Qh*Kh + Qh*Kl + Ql*Kh (3x mfma_f32_16x16x32_bf16);
// P bf16 via LDS row-major; O^T = V^T * P^T (V^T fragments straight from global Vt).
// Waves fully independent: no __syncthreads anywhere.
__global__ __launch_bounds__(256) void attn_k(const short* __restrict__ qh,
                                              const short* __restrict__ ql,
                                              const short* __restrict__ kh,
                                              const short* __restrict__ kl,
                                              const short* __restrict__ vt,
                                              const int* __restrict__ nodeof,
                                              const float* __restrict__ gw,
                                              const unsigned char* __restrict__ adj,
                                              float* __restrict__ ao) {
  __shared__ __align__(16) short p_s[4][32 * 72];   // per-wave P (32x64, ld=72) / reused as O f32 (32x36)
  __shared__ float aw_s[4][64];                     // per-wave: [0..31] alpha, [32..63] 1/l
  int t = threadIdx.x;
  int wid = t >> 6, lane = t & 63, quad = lane >> 4, l16 = lane & 15;
  int bh = blockIdx.y, b = bh >> 3, h = bh & 7;
  int q0 = blockIdx.x * 128 + wid * 32;
  size_t base = (size_t)bh * 32768;
  short* pw = &p_s[wid][0];
  float* aw = &aw_s[wid][0];

  bf16x8 qhf[2], qlf[2];
#pragma unroll
  for (int mi = 0; mi < 2; ++mi) {
    size_t off = base + (size_t)(q0 + mi * 16 + l16) * 32 + quad * 8;
    qhf[mi] = *(const bf16x8*)(qh + off);
    qlf[mi] = *(const bf16x8*)(ql + off);
  }
  int irow[2][4]; float grq[2][4];
#pragma unroll
  for (int mi = 0; mi < 2; ++mi)
#pragma unroll
    for (int r = 0; r < 4; ++r) {
      int qr = q0 + mi * 16 + quad * 4 + r;
      int in_ = nodeof[b * 1024 + qr];
      irow[mi][r] = in_;
      grq[mi][r] = (in_ >= 0) ? gw[((size_t)b * NN + in_) * NH + h] : 0.f;
    }
  const unsigned char* adjB = adj + (size_t)b * NN * NN;

  f32x4 ot[2][2];
#pragma unroll
  for (int mi = 0; mi < 2; ++mi)
#pragma unroll
    for (int nq = 0; nq < 2; ++nq) ot[mi][nq] = (f32x4){0.f, 0.f, 0.f, 0.f};
  float m_r[2][4], l_r[2][4];
#pragma unroll
  for (int mi = 0; mi < 2; ++mi)
#pragma unroll
    for (int r = 0; r < 4; ++r) { m_r[mi][r] = -1e30f; l_r[mi][r] = 0.f; }

  for (int ch = 0; ch < 16; ++ch) {
    int c0 = ch * 64;
    bf16x8 khf[4], klf[4];
#pragma unroll
    for (int ni = 0; ni < 4; ++ni) {
      size_t off = base + (size_t)(c0 + ni * 16 + l16) * 32 + quad * 8;
      khf[ni] = *(const bf16x8*)(kh + off);
      klf[ni] = *(const bf16x8*)(kl + off);
    }
    bf16x8 vaf[2][2];
#pragma unroll
    for (int mi = 0; mi < 2; ++mi)
#pragma unroll
      for (int ks = 0; ks < 2; ++ks)
        vaf[mi][ks] = *(const bf16x8*)(vt + base + (size_t)(mi * 16 + l16) * 1024 +
                                       c0 + ks * 32 + quad * 8);
    int jn[4]; float gcn[4];
#pragma unroll
    for (int ni = 0; ni < 4; ++ni) {
      int j = nodeof[b * 1024 + c0 + ni * 16 + l16];
      jn[ni] = j;
      gcn[ni] = (j >= 0) ? gw[((size_t)b * NN + j) * NH + h] : 0.f;
    }
    // S = Q K^T, split-bf16 (drop Ql*Kl, ~2^-18 relative)
    f32x4 s[2][4];
#pragma unroll
    for (int mi = 0; mi < 2; ++mi)
#pragma unroll
      for (int ni = 0; ni < 4; ++ni) {
        f32x4 a = (f32x4){0.f, 0.f, 0.f, 0.f};
        a = __builtin_amdgcn_mfma_f32_16x16x32_bf16(qhf[mi], khf[ni], a, 0, 0, 0);
        a = __builtin_amdgcn_mfma_f32_16x16x32_bf16(qhf[mi], klf[ni], a, 0, 0, 0);
        a = __builtin_amdgcn_mfma_f32_16x16x32_bf16(qlf[mi], khf[ni], a, 0, 0, 0);
        s[mi][ni] = a;
      }
    // graph modulation (scale folded into Q upstream)
#pragma unroll
    for (int mi = 0; mi < 2; ++mi)
#pragma unroll
      for (int r = 0; r < 4; ++r) {
        int in_ = irow[mi][r];
        if (in_ >= 0) {
          const unsigned char* ar = adjB + (size_t)in_ * NN;
          float g = grq[mi][r];
#pragma unroll
          for (int ni = 0; ni < 4; ++ni)
            if (jn[ni] >= 0 && ar[jn[ni]]) s[mi][ni][r] += g * gcn[ni];
        }
      }
    // online softmax; rows live in C-layout (row=quad*4+r), reduce over l16 group
#pragma unroll
    for (int mi = 0; mi < 2; ++mi)
#pragma unroll
      for (int r = 0; r < 4; ++r) {
        float mx = fmaxf(fmaxf(s[mi][0][r], s[mi][1][r]), fmaxf(s[mi][2][r], s[mi][3][r]));
        mx = fmaxf(mx, __shfl_xor(mx, 1));
        mx = fmaxf(mx, __shfl_xor(mx, 2));
        mx = fmaxf(mx, __shfl_xor(mx, 4));
        mx = fmaxf(mx, __shfl_xor(mx, 8));
        float mn = fmaxf(m_r[mi][r], mx);
        float al = __expf(m_r[mi][r] - mn);
        m_r[mi][r] = mn;
        float e0 = __expf(s[mi][0][r] - mn);
        float e1 = __expf(s[mi][1][r] - mn);
        float e2 = __expf(s[mi][2][r] - mn);
        float e3 = __expf(s[mi][3][r] - mn);
        float ls = e0 + e1 + e2 + e3;
        ls += __shfl_xor(ls, 1);
        ls += __shfl_xor(ls, 2);
        ls += __shfl_xor(ls, 4);
        ls += __shfl_xor(ls, 8);
        l_r[mi][r] = l_r[mi][r] * al + ls;
        int rl = mi * 16 + quad * 4 + r;
        if (l16 == 0) aw[rl] = al;
        int prow = rl * 72;
        pw[prow + 0 + l16] = f2bf(e0);
        pw[prow + 16 + l16] = f2bf(e1);
        pw[prow + 32 + l16] = f2bf(e2);
        pw[prow + 48 + l16] = f2bf(e3);
      }
    // O^T = V^T P^T  (O^T col = qrow = l16 per n-tile)
    float a0 = aw[l16], a1 = aw[16 + l16];
#pragma unroll
    for (int mi = 0; mi < 2; ++mi) { ot[mi][0] *= a0; ot[mi][1] *= a1; }
#pragma unroll
    for (int ks = 0; ks < 2; ++ks) {
      bf16x8 pb0 = *(const bf16x8*)(pw + l16 * 72 + ks * 32 + quad * 8);
      bf16x8 pb1 = *(const bf16x8*)(pw + (16 + l16) * 72 + ks * 32 + quad * 8);
      ot[0][0] = __builtin_amdgcn_mfma_f32_16x16x32_bf16(vaf[0][ks], pb0, ot[0][0], 0, 0, 0);
      ot[0][1] = __builtin_amdgcn_mfma_f32_16x16x32_bf16(vaf[0][ks], pb1, ot[0][1], 0, 0, 0);
      ot[1][0] = __builtin_amdgcn_mfma_f32_16x16x32_bf16(vaf[1][ks], pb0, ot[1][0], 0, 0, 0);
      ot[1][1] = __builtin_amdgcn_mfma_f32_16x16x32_bf16(vaf[1][ks], pb1, ot[1][1], 0, 0, 0);
    }
  }
  // finalize: 1/l, transpose O^T -> O via per-wave LDS, coalesced store
#pragma unroll
  for (int mi = 0; mi < 2; ++mi)
#pragma unroll
    for (int r = 0; r < 4; ++r)
      if (l16 == 0) aw[32 + mi * 16 + quad * 4 + r] = 1.f / l_r[mi][r];
  float li0 = aw[32 + l16], li1 = aw[48 + l16];
#pragma unroll
  for (int mi = 0; mi < 2; ++mi) { ot[mi][0] *= li0; ot[mi][1] *= li1; }
  float* os = (float*)pw;
#pragma unroll
  for (int mi = 0; mi < 2; ++mi)
#pragma unroll
    for (int nq = 0; nq < 2; ++nq)
#pragma unroll
      for (int r = 0; r < 4; ++r)
        os[(nq * 16 + l16) * 36 + mi * 16 + quad * 4 + r] = ot[mi][nq][r];
  int qrow = lane >> 1, dh = (lane & 1) * 16;
  size_t ob = (size_t)(b * 1024 + q0 + qrow) * 256 + h * 32 + dh;
#pragma unroll
  for (int k = 0; k < 4; ++k) {
    float4 v4 = *(float4*)&os[qrow * 36 + dh + k * 4];
    *(float4*)&ao[ob + k * 4] = v4;
  }
}

// ---------------- proj GEMM + bias + transposed store ----------------
__global__ __launch_bounds__(256) void proj_k(const float* __restrict__ ao,
                                              const float* __restrict__ wT,
                                              const float* __restrict__ bias,
                                              float* __restrict__ out) {
  __shared__ float a_s[16][68];
  __shared__ float b_s[16][68];
  __shared__ float c_s[64][68];
  int m0 = blockIdx.x * 64, n0 = blockIdx.y * 64;
  int b = m0 >> 10, p0 = m0 & 1023;
  int t = threadIdx.x, tx = t & 15, ty = t >> 4;
  float acc[4][4] = {};
  for (int k0 = 0; k0 < 256; k0 += 16) {
    {
      int kk = t & 15, mm = t >> 4;
#pragma unroll
      for (int r = 0; r < 4; ++r) {
        int m = mm + r * 16;
        a_s[kk][m] = ao[(size_t)(m0 + m) * 256 + k0 + kk];
      }
      int mB = t & 63, kb = t >> 6;
#pragma unroll
      for (int r2 = 0; r2 < 4; ++r2) {
        int kk2 = kb * 4 + r2;
        b_s[kk2][mB] = wT[(k0 + kk2) * 256 + n0 + mB];
      }
    }
    __syncthreads();
#pragma unroll
    for (int kk = 0; kk < 16; ++kk) {
      float4 av = *(const float4*)&a_s[kk][ty * 4];
      float4 bv = *(const float4*)&b_s[kk][tx * 4];
      FMA16(acc, av, bv)
    }
    __syncthreads();
  }
#pragma unroll
  for (int i = 0; i < 4; ++i)
#pragma unroll
    for (int j = 0; j < 4; ++j) c_s[tx * 4 + j][ty * 4 + i] = acc[i][j];
  __syncthreads();
  {
    int cl = t >> 2, pg = t & 3;
    float bv = bias[n0 + cl];
#pragma unroll
    for (int r = 0; r < 4; ++r) {
      int p = pg * 16 + r * 4;
      float4 v4 = {c_s[cl][p] + bv, c_s[cl][p + 1] + bv, c_s[cl][p + 2] + bv, c_s[cl][p + 3] + bv};
      *(float4*)&out[((size_t)b * 256 + n0 + cl) * 1024 + p0 + p] = v4;
    }
  }
}

extern "C" void kernel_launch(void* const* d_in, const int* in_sizes, int n_in,
                              void* d_out, int out_size, void* d_ws, size_t ws_size,
                              hipStream_t stream) {
  const float* x      = (const float*)d_in[0];
  const float* w_qkv  = (const float*)d_in[1];
  const float* w_proj = (const float*)d_in[2];
  const float* b_proj = (const float*)d_in[3];
  const float* g0W    = (const float*)d_in[4];
  const float* g0as   = (const float*)d_in[5];
  const float* g0ad   = (const float*)d_in[6];
  const float* g0b    = (const float*)d_in[7];
  const float* g1W    = (const float*)d_in[8];
  const float* g1as   = (const float*)d_in[9];
  const float* g1ad   = (const float*)d_in[10];
  const float* g1b    = (const float*)d_in[11];
  const float* wg2a   = (const float*)d_in[12];
  const float* bg2a   = (const float*)d_in[13];
  float* out = (float*)d_out;
  float* ws = (float*)d_ws;

  size_t o = 0;
  auto alloc = [&](size_t nf) { float* p = ws + o; o += (nf + 15) & ~(size_t)15; return p; };
  float* wqkvT  = alloc(256 * 768);
  float* wprojT = alloc(256 * 256);
  float* imp    = alloc(8 * 1024);
  int*   topi   = (int*)alloc(8 * 128);
  int*   nodeof = (int*)alloc(8 * 1024);
  float* rn     = alloc(8 * 128);
  float* feats  = alloc(8 * NN * 256);
  unsigned char* adj = (unsigned char*)alloc((8 * NN * NN + 3) / 4 + 16);
  float* h0     = alloc(8 * NN * 64);
  float* g0     = alloc(8 * NN * 64);
  float* h1     = alloc(8 * NN * 64);
  float* g1     = alloc(8 * NN * 64);
  float* asrc   = alloc(8 * 128);
  float* adst   = alloc(8 * 128);
  float* gwb    = alloc(8 * NN * 8);
  short* qh     = (short*)alloc(1048576);
  short* ql     = (short*)alloc(1048576);
  short* kh     = (short*)alloc(1048576);
  short* kl     = (short*)alloc(1048576);
  short* vt     = (short*)alloc(1048576);
  float* ao     = alloc((size_t)8 * 1024 * 256);
  if (ws_size < o * sizeof(float)) return;

  transpose_k<<<dim3(8, 24), dim3(32, 8), 0, stream>>>(w_qkv, wqkvT, 768, 256);
  transpose_k<<<dim3(8, 8), dim3(32, 8), 0, stream>>>(w_proj, wprojT, 256, 256);
  importance_k<<<32, 256, 0, stream>>>(x, imp);
  topk_k<<<8, 1024, 0, stream>>>(imp, topi, nodeof);
  feats_k<<<dim3(NN, 8), 256, 0, stream>>>(x, topi, feats, rn);
  adj_k<<<dim3(NN, 8), 128, 0, stream>>>(feats, rn, adj);
  gath_k<<<dim3(NN, 8), 64, 0, stream>>>(feats, g0W, g0as, g0ad, h0, asrc, adst, 256);
  gatsoft_k<<<dim3(NN, 8), 128, 0, stream>>>(h0, asrc, adst, adj, g0b, g0);
  gath_k<<<dim3(NN, 8), 64, 0, stream>>>(g0, g1W, g1as, g1ad, h1, asrc, adst, 64);
  gatsoft_k<<<dim3(NN, 8), 128, 0, stream>>>(h1, asrc, adst, adj, g1b, g1);
  g2a_k<<<dim3(NN, 8), 64, 0, stream>>>(g1, wg2a, bg2a, gwb);
  qkv_k<<<dim3(128, 12), 256, 0, stream>>>(x, wqkvT, qh, ql, kh, kl, vt);
  attn_k<<<dim3(8, 64), 256, 0, stream>>>(qh, ql, kh, kl, vt, nodeof, gwb, adj, ao);
  proj_k<<<dim3(128, 4), 256, 0, stream>>>(ao, wprojT, b_proj, out);
}